// Round 9
// baseline (35.147 us; speedup 1.0000x reference)
//
#include <hip/hip_runtime.h>
#include <hip/hip_bf16.h>
#include <hip/hip_fp16.h>

// Problem constants
#define D    128
#define NQ   2048
#define NP   256
#define H1   128
#define H2   64
#define QB   4     // q-rows per main block -> grid 512 = 2 blocks/CU

typedef __attribute__((ext_vector_type(8))) _Float16 f16x8;
typedef __attribute__((ext_vector_type(2))) __fp16   h16x2;   // cvt_pkrtz/fdot2 type
typedef __attribute__((ext_vector_type(4))) float    f32x4;

// ---------------------------------------------------------------------------
// Workspace layout (float units):
//   qh16  [NQ][H1] f16   q @ W1q^T + b1        off 0       (131072 f32 slots)
//   ph16  [NP][H1] f16   p @ W1p^T             off 131072  (16384)
//   w2f   [H2][H1] f16   cast of W2            off 147456  (4096)
//   base  [NQ][NP] f32                          off 151552  (524288)
// ---------------------------------------------------------------------------
#define OFF_QH16 0
#define OFF_PH16 131072
#define OFF_W2F  147456
#define OFF_BASE 151552

// prep grid layout: 545 blocks (~2.1/CU, no 17-block tail round)
#define PQ_BLKS  256            // proj-q, 8 rows each
#define PP_BLKS  32             // proj-p, 8 rows each
#define W2_BLK   (PQ_BLKS + PP_BLKS)          // 288
#define BASE0    (W2_BLK + 1)                 // 289
#define BASE_BLKS 256           // base, 8 q-rows each
#define PREP_GRID (BASE0 + BASE_BLKS)         // 545

static __device__ __forceinline__ f16x8 cvt8(float4 a, float4 b) {
    f16x8 f;
    f[0] = (_Float16)a.x; f[1] = (_Float16)a.y;
    f[2] = (_Float16)a.z; f[3] = (_Float16)a.w;
    f[4] = (_Float16)b.x; f[5] = (_Float16)b.y;
    f[6] = (_Float16)b.z; f[7] = (_Float16)b.w;
    return f;
}

// ---------------------------------------------------------------------------
// Launch 1 (no internal deps). 8-row blocks: A-frag loads row r0+(lo&7)
// (rows 8..15 duplicate 0..7, harmless), stores gated to rows < 8.
// ---------------------------------------------------------------------------
__global__ void __launch_bounds__(256)
prep_base_kernel(const float* __restrict__ q, const float* __restrict__ p,
                 const float* __restrict__ W1, const float* __restrict__ b1,
                 const float* __restrict__ W2,
                 _Float16* __restrict__ qh16, _Float16* __restrict__ ph16,
                 _Float16* __restrict__ w2f, float* __restrict__ baseM) {
    int bx = blockIdx.x, tid = threadIdx.x;
    int lane = tid & 63, w = tid >> 6;
    int lo = lane & 15, g = lane >> 4;

    if (bx == W2_BLK) {
        for (int i = tid; i < H2 * H1; i += 256)
            w2f[i] = (_Float16)W2[i];
        return;
    }

    if (bx < W2_BLK) {                    // ---- projection blocks (8 rows) ----
        bool isQ = bx < PQ_BLKS;
        const float* X = isQ ? q : p;
        int r0 = isQ ? bx * 8 : (bx - PQ_BLKS) * 8;
        int woff = isQ ? 0 : D;
        _Float16* hout = isQ ? qh16 : ph16;
        int ob = w * 32;
        int rowld = r0 + (lo & 7);

        float4 ar[4][2], br[2][4][2];
        #pragma unroll
        for (int ks = 0; ks < 4; ++ks) {
            const float* src = X + rowld * D + ks * 32 + g * 8;
            ar[ks][0] = *(const float4*)src;
            ar[ks][1] = *(const float4*)(src + 4);
        }
        #pragma unroll
        for (int n = 0; n < 2; ++n)
            #pragma unroll
            for (int ks = 0; ks < 4; ++ks) {
                const float* src = W1 + (ob + n * 16 + lo) * (2 * D) + woff + ks * 32 + g * 8;
                br[n][ks][0] = *(const float4*)src;
                br[n][ks][1] = *(const float4*)(src + 4);
            }
        f16x8 A[4];
        #pragma unroll
        for (int ks = 0; ks < 4; ++ks) A[ks] = cvt8(ar[ks][0], ar[ks][1]);

        f32x4 C[2];
        C[0] = (f32x4){0.f, 0.f, 0.f, 0.f};
        C[1] = (f32x4){0.f, 0.f, 0.f, 0.f};
        #pragma unroll
        for (int n = 0; n < 2; ++n)
            #pragma unroll
            for (int ks = 0; ks < 4; ++ks)
                C[n] = __builtin_amdgcn_mfma_f32_16x16x32_f16(
                    A[ks], cvt8(br[n][ks][0], br[n][ks][1]), C[n], 0, 0, 0);
        if (g < 2) {                      // rows g*4+r in 0..7 only
            #pragma unroll
            for (int n = 0; n < 2; ++n) {
                int o = ob + n * 16 + lo;
                float bv = isQ ? b1[o] : 0.f;
                #pragma unroll
                for (int r = 0; r < 4; ++r)
                    hout[(r0 + g * 4 + r) * H1 + o] = (_Float16)(C[n][r] + bv);
            }
        }
        return;
    }

    // ---- base tiles (8 q-rows x 256 p): wave w owns p [64w,64w+64)
    int r0 = (bx - BASE0) * 8;
    int rowld = r0 + (lo & 7);

    float4 qr[4][2];
    #pragma unroll
    for (int ks = 0; ks < 4; ++ks) {
        const float* src = q + rowld * D + ks * 32 + g * 8;
        qr[ks][0] = *(const float4*)src;
        qr[ks][1] = *(const float4*)(src + 4);
    }
    float4 pr_[4][4][2];
    #pragma unroll
    for (int n = 0; n < 4; ++n) {
        int pcol = w * 64 + n * 16 + lo;
        #pragma unroll
        for (int ks = 0; ks < 4; ++ks) {
            const float* src = p + pcol * D + ks * 32 + g * 8;
            pr_[n][ks][0] = *(const float4*)src;
            pr_[n][ks][1] = *(const float4*)(src + 4);
        }
    }
    f16x8 A[4];
    float asq = 0.f;
    #pragma unroll
    for (int ks = 0; ks < 4; ++ks) {
        float4 a = qr[ks][0], b = qr[ks][1];
        asq += a.x * a.x + a.y * a.y + a.z * a.z + a.w * a.w
             + b.x * b.x + b.y * b.y + b.z * b.z + b.w * b.w;
        A[ks] = cvt8(a, b);
    }
    asq += __shfl_xor(asq, 16);
    asq += __shfl_xor(asq, 32);           // lane with lo=j holds qn[r0+j]

    f32x4 C[4];
    float psq[4];
    #pragma unroll
    for (int n = 0; n < 4; ++n) {
        C[n] = (f32x4){0.f, 0.f, 0.f, 0.f};
        psq[n] = 0.f;
        #pragma unroll
        for (int ks = 0; ks < 4; ++ks) {
            float4 a = pr_[n][ks][0], b = pr_[n][ks][1];
            psq[n] += a.x * a.x + a.y * a.y + a.z * a.z + a.w * a.w
                    + b.x * b.x + b.y * b.y + b.z * b.z + b.w * b.w;
            C[n] = __builtin_amdgcn_mfma_f32_16x16x32_f16(A[ks], cvt8(a, b), C[n], 0, 0, 0);
        }
        psq[n] += __shfl_xor(psq[n], 16);
        psq[n] += __shfl_xor(psq[n], 32);
    }
    if (g < 2) {                          // rows g*4+r in 0..7 only
        #pragma unroll
        for (int n = 0; n < 4; ++n) {
            int pcol = w * 64 + n * 16 + lo;
            #pragma unroll
            for (int r = 0; r < 4; ++r) {
                float qnv = __shfl(asq, g * 4 + r);
                baseM[(r0 + g * 4 + r) * NP + pcol] =
                    fmaxf(qnv + psq[n] - 2.f * C[n][r], 0.f);
            }
        }
    }
}

// ---------------------------------------------------------------------------
// Main: QB=4 q x 256 p per block, grid 512 (2 blocks/CU = 2 waves/SIMD).
// 1-deep software pipeline over units u=(qq,hh): epilogue(u-1) and finish(q)
// run in the MFMA shadow of unit u. C double-buffered by u-parity; all
// indices compile-time via full unroll. P+Af register-resident.
// ---------------------------------------------------------------------------
__global__ void __launch_bounds__(256, 2)
main_kernel(const _Float16* __restrict__ qh16, const _Float16* __restrict__ ph16,
            const _Float16* __restrict__ w2f,
            const float* __restrict__ b2, const float* __restrict__ w3,
            const float* __restrict__ b3,
            const float* __restrict__ baseM, float* __restrict__ out) {
    __shared__ _Float16 qh_s[QB * H1];   // 1 KB
    int tid = threadIdx.x, lane = tid & 63, w = tid >> 6;
    int lo = lane & 15, g = lane >> 4;
    int q0 = blockIdx.x * QB;

    if (tid < (QB * H1) / 8)
        ((uint4*)qh_s)[tid] = ((const uint4*)(qh16 + q0 * H1))[tid];

    // prefetch baseM (hidden under setup)
    int pmine = w * 64 + lane;
    float bse[QB];
    #pragma unroll
    for (int qq = 0; qq < QB; ++qq)
        bse[qq] = baseM[(q0 + qq) * NP + pmine];

    // ph fragments [n][ks], register-resident (64 VGPR)
    f16x8 P[4][4];
    #pragma unroll
    for (int n = 0; n < 4; ++n)
        #pragma unroll
        for (int ks = 0; ks < 4; ++ks)
            P[n][ks] = *(const f16x8*)(ph16 + (w * 64 + n * 16 + lo) * H1 + ks * 32 + g * 8);

    // W2 fragments [m][ks], register-resident (64 VGPR)
    f16x8 Af[4][4];
    #pragma unroll
    for (int m = 0; m < 4; ++m)
        #pragma unroll
        for (int ks = 0; ks < 4; ++ks)
            Af[m][ks] = *(const f16x8*)(w2f + (m * 16 + lo) * H1 + ks * 32 + g * 8);

    // packed epilogue constants: o = m*16 + g*4 + {0..3}
    h16x2 b2p[4][2], w3p[4][2];
    #pragma unroll
    for (int m = 0; m < 4; ++m) {
        float4 bb = *(const float4*)(b2 + m * 16 + g * 4);
        float4 ww = *(const float4*)(w3 + m * 16 + g * 4);
        b2p[m][0] = __builtin_amdgcn_cvt_pkrtz(bb.x, bb.y);
        b2p[m][1] = __builtin_amdgcn_cvt_pkrtz(bb.z, bb.w);
        w3p[m][0] = __builtin_amdgcn_cvt_pkrtz(ww.x, ww.y);
        w3p[m][1] = __builtin_amdgcn_cvt_pkrtz(ww.z, ww.w);
    }
    float b3v = b3[0];
    const f16x8 zz = {};
    const h16x2 z2 = {};
    const f32x4 Zv = (f32x4){0.f, 0.f, 0.f, 0.f};
    __syncthreads();

    f16x8 qkr[2][4];                     // qk ring (by q parity)
    #pragma unroll
    for (int ks = 0; ks < 4; ++ks)
        qkr[0][ks] = *(const f16x8*)(qh_s + ks * 32 + g * 8);

    f32x4 Cb[2][4][2];                   // C ring (by unit parity)
    float zp[QB][4];

    #pragma unroll
    for (int u = 0; u <= 2 * QB; ++u) {
        // ---- issue unit u: B-build + 32 MFMAs ----
        if (u < 2 * QB) {
            const int qq = u >> 1, hh = u & 1, cu = u & 1;
            #pragma unroll
            for (int ks = 0; ks < 4; ++ks) {
                f16x8 B0 = __builtin_elementwise_max(P[2 * hh + 0][ks] + qkr[qq & 1][ks], zz);
                f16x8 B1 = __builtin_elementwise_max(P[2 * hh + 1][ks] + qkr[qq & 1][ks], zz);
                #pragma unroll
                for (int m = 0; m < 4; ++m) {
                    if (ks == 0) {       // constant zero acc: no per-unit C re-zero
                        Cb[cu][m][0] = __builtin_amdgcn_mfma_f32_16x16x32_f16(Af[m][0], B0, Zv, 0, 0, 0);
                        Cb[cu][m][1] = __builtin_amdgcn_mfma_f32_16x16x32_f16(Af[m][0], B1, Zv, 0, 0, 0);
                    } else {
                        Cb[cu][m][0] = __builtin_amdgcn_mfma_f32_16x16x32_f16(Af[m][ks], B0, Cb[cu][m][0], 0, 0, 0);
                        Cb[cu][m][1] = __builtin_amdgcn_mfma_f32_16x16x32_f16(Af[m][ks], B1, Cb[cu][m][1], 0, 0, 0);
                    }
                }
            }
            // prefetch next q's qk during hh==0 (lands in opposite ring slot)
            if (hh == 0 && qq + 1 < QB) {
                #pragma unroll
                for (int ks = 0; ks < 4; ++ks)
                    qkr[(qq + 1) & 1][ks] = *(const f16x8*)(qh_s + (qq + 1) * H1 + ks * 32 + g * 8);
            }
        }
        // ---- shadow: epilogue of unit u-1 ----
        if (u > 0) {
            const int pu = u - 1, pq = pu >> 1, ph = pu & 1, pc = pu & 1;
            #pragma unroll
            for (int n2 = 0; n2 < 2; ++n2) {
                float sA = 0.f, sB = 0.f;
                #pragma unroll
                for (int m = 0; m < 4; ++m) {
                    h16x2 c01 = __builtin_amdgcn_cvt_pkrtz(Cb[pc][m][n2][0], Cb[pc][m][n2][1]);
                    h16x2 c23 = __builtin_amdgcn_cvt_pkrtz(Cb[pc][m][n2][2], Cb[pc][m][n2][3]);
                    h16x2 h01 = __builtin_elementwise_max(c01 + b2p[m][0], z2);
                    h16x2 h23 = __builtin_elementwise_max(c23 + b2p[m][1], z2);
                    sA = __builtin_amdgcn_fdot2(h01, w3p[m][0], sA, false);
                    sB = __builtin_amdgcn_fdot2(h23, w3p[m][1], sB, false);
                }
                zp[pq][2 * ph + n2] = sA + sB;
            }
        }
        // ---- shadow: finish q = u/2 - 1 (shuffles + softplus + store) ----
        if (u >= 2 && (u & 1) == 0) {
            const int fq = (u - 2) >> 1;
            float v[4], sh[4];
            #pragma unroll
            for (int i = 0; i < 4; ++i) v[i] = zp[fq][i];
            #pragma unroll
            for (int i = 0; i < 4; ++i) sh[i] = __shfl_xor(v[i], 16);
            #pragma unroll
            for (int i = 0; i < 4; ++i) v[i] += sh[i];
            #pragma unroll
            for (int i = 0; i < 4; ++i) sh[i] = __shfl_xor(v[i], 32);
            #pragma unroll
            for (int i = 0; i < 4; ++i) v[i] += sh[i];
            float z = (g == 0) ? v[0] : (g == 1) ? v[1] : (g == 2) ? v[2] : v[3];
            z += b3v;
            float sp = fmaxf(z, 0.f) + __logf(1.f + __expf(-fabsf(z)));
            out[(q0 + fq) * NP + pmine] = bse[fq] * (1.f + sp);   // cw ~= alpha
        }
    }
}

extern "C" void kernel_launch(void* const* d_in, const int* in_sizes, int n_in,
                              void* d_out, int out_size, void* d_ws, size_t ws_size,
                              hipStream_t stream) {
    const float* q  = (const float*)d_in[0];
    const float* pr = (const float*)d_in[1];
    const float* W1 = (const float*)d_in[2];
    const float* b1 = (const float*)d_in[3];
    const float* W2 = (const float*)d_in[4];
    const float* b2 = (const float*)d_in[5];
    const float* W3 = (const float*)d_in[6];
    const float* b3 = (const float*)d_in[7];
    float* out = (float*)d_out;
    float* ws  = (float*)d_ws;

    _Float16* qh16 = (_Float16*)(ws + OFF_QH16);
    _Float16* ph16 = (_Float16*)(ws + OFF_PH16);
    _Float16* w2f  = (_Float16*)(ws + OFF_W2F);
    float* baseM = ws + OFF_BASE;

    prep_base_kernel<<<PREP_GRID, 256, 0, stream>>>(q, pr, W1, b1, W2,
                                                    qh16, ph16, w2f, baseM);
    main_kernel<<<NQ / QB, 256, 0, stream>>>(qh16, ph16, w2f, b2, W3, b3, baseM, out);
}

// Round 10
// 32.502 us; speedup vs baseline: 1.0814x; 1.0814x over previous
//
#include <hip/hip_runtime.h>
#include <hip/hip_bf16.h>
#include <hip/hip_fp16.h>

// Problem constants
#define D    128
#define NQ   2048
#define NP   256
#define H1   128
#define H2   64
#define QB   4     // q-rows per main block -> grid 512 = 2 blocks/CU

typedef __attribute__((ext_vector_type(8))) _Float16 f16x8;
typedef __attribute__((ext_vector_type(2))) __fp16   h16x2;   // cvt_pkrtz/fdot2 type
typedef __attribute__((ext_vector_type(4))) float    f32x4;

// ---------------------------------------------------------------------------
// Workspace layout (float units):
//   qh16  [NQ][H1] f16   q @ W1q^T + b1        off 0       (131072 f32 slots)
//   ph16  [NP][H1] f16   p @ W1p^T             off 131072  (16384)
//   w2f   [H2][H1] f16   cast of W2            off 147456  (4096)
// ---------------------------------------------------------------------------
#define OFF_QH16 0
#define OFF_PH16 131072
#define OFF_W2F  147456

static __device__ __forceinline__ f16x8 cvt8(float4 a, float4 b) {
    f16x8 f;
    f[0] = (_Float16)a.x; f[1] = (_Float16)a.y;
    f[2] = (_Float16)a.z; f[3] = (_Float16)a.w;
    f[4] = (_Float16)b.x; f[5] = (_Float16)b.y;
    f[6] = (_Float16)b.z; f[7] = (_Float16)b.w;
    return f;
}

// ---------------------------------------------------------------------------
// Prep (proj only, 145 blocks):
//   bx   0..127  : q-proj -> qh16 (16 q rows each), bias folded
//   bx 128..143  : p-proj -> ph16 (16 p rows each)
//   bx 144       : W2 -> f16 cast
// All global loads hoisted ahead of MFMA chains.
// ---------------------------------------------------------------------------
__global__ void __launch_bounds__(256)
prep_kernel(const float* __restrict__ q, const float* __restrict__ p,
            const float* __restrict__ W1, const float* __restrict__ b1,
            const float* __restrict__ W2,
            _Float16* __restrict__ qh16, _Float16* __restrict__ ph16,
            _Float16* __restrict__ w2f) {
    int bx = blockIdx.x, tid = threadIdx.x;
    int lane = tid & 63, w = tid >> 6;
    int lo = lane & 15, g = lane >> 4;

    if (bx == 144) {
        for (int i = tid; i < H2 * H1; i += 256)
            w2f[i] = (_Float16)W2[i];
        return;
    }

    bool isQ = bx < 128;
    const float* X = isQ ? q : p;
    int r0 = isQ ? bx * 16 : (bx - 128) * 16;
    int woff = isQ ? 0 : D;
    _Float16* hout = isQ ? qh16 : ph16;
    int ob = w * 32;

    float4 ar[4][2], br[2][4][2];
    #pragma unroll
    for (int ks = 0; ks < 4; ++ks) {
        const float* src = X + (r0 + lo) * D + ks * 32 + g * 8;
        ar[ks][0] = *(const float4*)src;
        ar[ks][1] = *(const float4*)(src + 4);
    }
    #pragma unroll
    for (int n = 0; n < 2; ++n)
        #pragma unroll
        for (int ks = 0; ks < 4; ++ks) {
            const float* src = W1 + (ob + n * 16 + lo) * (2 * D) + woff + ks * 32 + g * 8;
            br[n][ks][0] = *(const float4*)src;
            br[n][ks][1] = *(const float4*)(src + 4);
        }
    f16x8 A[4];
    #pragma unroll
    for (int ks = 0; ks < 4; ++ks) A[ks] = cvt8(ar[ks][0], ar[ks][1]);

    f32x4 C[2];
    C[0] = (f32x4){0.f, 0.f, 0.f, 0.f};
    C[1] = (f32x4){0.f, 0.f, 0.f, 0.f};
    #pragma unroll
    for (int n = 0; n < 2; ++n)
        #pragma unroll
        for (int ks = 0; ks < 4; ++ks)
            C[n] = __builtin_amdgcn_mfma_f32_16x16x32_f16(
                A[ks], cvt8(br[n][ks][0], br[n][ks][1]), C[n], 0, 0, 0);
    #pragma unroll
    for (int n = 0; n < 2; ++n) {
        int o = ob + n * 16 + lo;
        float bv = isQ ? b1[o] : 0.f;
        #pragma unroll
        for (int r = 0; r < 4; ++r)
            hout[(r0 + g * 4 + r) * H1 + o] = (_Float16)(C[n][r] + bv);
    }
}

// ---------------------------------------------------------------------------
// Main (R8 loop + fused distance): QB=4 q x 256 p per block, grid 512
// (2 blocks/CU = 2 waves/SIMD). Wave w owns p [64w,64w+64).
// Setup computes base = max(qn+pn-2*q.p,0) in-wave via f16 MFMA with
// A-rows = q0+(lo&3) (rows duplicate across g) -> lane (g,lo) holds its own
// p-column's distances for all 4 q in C[g][qq]: pure in-lane selects.
// Then the R8 MLP loop: C[o,p]=sum_h W2[o,h]*relu(qh+ph) via f16 MFMA,
// P+Af register-resident, packed-f16 epilogue, fast softplus, cw ~= alpha.
// ---------------------------------------------------------------------------
__global__ void __launch_bounds__(256, 2)
main_kernel(const _Float16* __restrict__ qh16, const _Float16* __restrict__ ph16,
            const _Float16* __restrict__ w2f,
            const float* __restrict__ qraw, const float* __restrict__ praw,
            const float* __restrict__ b2, const float* __restrict__ w3,
            const float* __restrict__ b3, float* __restrict__ out) {
    __shared__ _Float16 qh_s[QB * H1];   // 1 KB
    int tid = threadIdx.x, lane = tid & 63, w = tid >> 6;
    int lo = lane & 15, g = lane >> 4;
    int q0 = blockIdx.x * QB;

    if (tid < (QB * H1) / 8)
        ((uint4*)qh_s)[tid] = ((const uint4*)(qh16 + q0 * H1))[tid];

    // ================= fused distance block =================
    int qrow = q0 + (lo & 3);            // rows duplicate across lanes
    float4 qr[4][2];
    #pragma unroll
    for (int ks = 0; ks < 4; ++ks) {
        const float* src = qraw + qrow * D + ks * 32 + g * 8;
        qr[ks][0] = *(const float4*)src;
        qr[ks][1] = *(const float4*)(src + 4);
    }
    f16x8 Ad[4];
    float asq = 0.f;
    #pragma unroll
    for (int ks = 0; ks < 4; ++ks) {
        float4 a = qr[ks][0], b = qr[ks][1];
        asq += a.x * a.x + a.y * a.y + a.z * a.z + a.w * a.w
             + b.x * b.x + b.y * b.y + b.z * b.z + b.w * b.w;
        Ad[ks] = cvt8(a, b);
    }
    asq += __shfl_xor(asq, 16);
    asq += __shfl_xor(asq, 32);          // full qn[qrow] on every lane

    f32x4 Cd[4];
    float psq[4];
    #pragma unroll
    for (int n = 0; n < 4; ++n) {
        int pcol = w * 64 + n * 16 + lo;
        Cd[n] = (f32x4){0.f, 0.f, 0.f, 0.f};
        psq[n] = 0.f;
        #pragma unroll
        for (int ks = 0; ks < 4; ++ks) {
            const float* src = praw + pcol * D + ks * 32 + g * 8;
            float4 a = *(const float4*)src, b = *(const float4*)(src + 4);
            psq[n] += a.x * a.x + a.y * a.y + a.z * a.z + a.w * a.w
                    + b.x * b.x + b.y * b.y + b.z * b.z + b.w * b.w;
            Cd[n] = __builtin_amdgcn_mfma_f32_16x16x32_f16(Ad[ks], cvt8(a, b), Cd[n], 0, 0, 0);
        }
        psq[n] += __shfl_xor(psq[n], 16);
        psq[n] += __shfl_xor(psq[n], 32);   // full pn[pcol] on every lane
    }
    // per-lane: p = w*64 + g*16 + lo -> frag n = g
    float pnm = (g == 0) ? psq[0] : (g == 1) ? psq[1] : (g == 2) ? psq[2] : psq[3];
    float bse[QB];
    #pragma unroll
    for (int qq = 0; qq < QB; ++qq) {
        float qn = __shfl(asq, qq);      // lane qq holds row qq (qq<4)
        float dg = (g == 0) ? Cd[0][qq] : (g == 1) ? Cd[1][qq]
                 : (g == 2) ? Cd[2][qq] : Cd[3][qq];
        bse[qq] = fmaxf(qn + pnm - 2.f * dg, 0.f);
    }
    // ========================================================

    // ph fragments [n][ks], register-resident (64 VGPR)
    f16x8 P[4][4];
    #pragma unroll
    for (int n = 0; n < 4; ++n)
        #pragma unroll
        for (int ks = 0; ks < 4; ++ks)
            P[n][ks] = *(const f16x8*)(ph16 + (w * 64 + n * 16 + lo) * H1 + ks * 32 + g * 8);

    // W2 fragments [m][ks], register-resident (64 VGPR)
    f16x8 Af[4][4];
    #pragma unroll
    for (int m = 0; m < 4; ++m)
        #pragma unroll
        for (int ks = 0; ks < 4; ++ks)
            Af[m][ks] = *(const f16x8*)(w2f + (m * 16 + lo) * H1 + ks * 32 + g * 8);

    // packed epilogue constants: o = m*16 + g*4 + {0..3}
    h16x2 b2p[4][2], w3p[4][2];
    #pragma unroll
    for (int m = 0; m < 4; ++m) {
        float4 bb = *(const float4*)(b2 + m * 16 + g * 4);
        float4 ww = *(const float4*)(w3 + m * 16 + g * 4);
        b2p[m][0] = __builtin_amdgcn_cvt_pkrtz(bb.x, bb.y);
        b2p[m][1] = __builtin_amdgcn_cvt_pkrtz(bb.z, bb.w);
        w3p[m][0] = __builtin_amdgcn_cvt_pkrtz(ww.x, ww.y);
        w3p[m][1] = __builtin_amdgcn_cvt_pkrtz(ww.z, ww.w);
    }
    float b3v = b3[0];
    const f16x8 zz = {};
    const h16x2 z2 = {};
    const f32x4 Zv = (f32x4){0.f, 0.f, 0.f, 0.f};
    int pmine = w * 64 + lane;
    __syncthreads();

    // qk fragments, prefetched one q ahead (fully unrolled -> static indices)
    f16x8 qk[QB][4];
    #pragma unroll
    for (int ks = 0; ks < 4; ++ks)
        qk[0][ks] = *(const f16x8*)(qh_s + 0 * H1 + ks * 32 + g * 8);

    #pragma unroll
    for (int qq = 0; qq < QB; ++qq) {
        float zp[4];
        #pragma unroll
        for (int hh = 0; hh < 2; ++hh) {
            f32x4 C[4][2];
            #pragma unroll
            for (int ks = 0; ks < 4; ++ks) {
                f16x8 B0 = __builtin_elementwise_max(P[2 * hh + 0][ks] + qk[qq][ks], zz);
                f16x8 B1 = __builtin_elementwise_max(P[2 * hh + 1][ks] + qk[qq][ks], zz);
                #pragma unroll
                for (int m = 0; m < 4; ++m) {
                    if (ks == 0) {   // constant zero acc: no per-q C re-zero
                        C[m][0] = __builtin_amdgcn_mfma_f32_16x16x32_f16(Af[m][0], B0, Zv, 0, 0, 0);
                        C[m][1] = __builtin_amdgcn_mfma_f32_16x16x32_f16(Af[m][0], B1, Zv, 0, 0, 0);
                    } else {
                        C[m][0] = __builtin_amdgcn_mfma_f32_16x16x32_f16(Af[m][ks], B0, C[m][0], 0, 0, 0);
                        C[m][1] = __builtin_amdgcn_mfma_f32_16x16x32_f16(Af[m][ks], B1, C[m][1], 0, 0, 0);
                    }
                }
            }
            // prefetch next q's qk while MFMAs drain (after first half)
            if (hh == 0 && qq + 1 < QB) {
                #pragma unroll
                for (int ks = 0; ks < 4; ++ks)
                    qk[qq + 1][ks] = *(const f16x8*)(qh_s + (qq + 1) * H1 + ks * 32 + g * 8);
            }
            // packed-f16 epilogue: h2 = relu(C+b2) (f16), z += h2 . w3 (dot2)
            #pragma unroll
            for (int n2 = 0; n2 < 2; ++n2) {
                float sA = 0.f, sB = 0.f;
                #pragma unroll
                for (int m = 0; m < 4; ++m) {
                    h16x2 c01 = __builtin_amdgcn_cvt_pkrtz(C[m][n2][0], C[m][n2][1]);
                    h16x2 c23 = __builtin_amdgcn_cvt_pkrtz(C[m][n2][2], C[m][n2][3]);
                    h16x2 h01 = __builtin_elementwise_max(c01 + b2p[m][0], z2);
                    h16x2 h23 = __builtin_elementwise_max(c23 + b2p[m][1], z2);
                    sA = __builtin_amdgcn_fdot2(h01, w3p[m][0], sA, false);
                    sB = __builtin_amdgcn_fdot2(h23, w3p[m][1], sB, false);
                }
                zp[2 * hh + n2] = sA + sB;
            }
        }
        // batched cross-lane reduction (ILP across the 4 values)
        float sh[4];
        #pragma unroll
        for (int i = 0; i < 4; ++i) sh[i] = __shfl_xor(zp[i], 16);
        #pragma unroll
        for (int i = 0; i < 4; ++i) zp[i] += sh[i];
        #pragma unroll
        for (int i = 0; i < 4; ++i) sh[i] = __shfl_xor(zp[i], 32);
        #pragma unroll
        for (int i = 0; i < 4; ++i) zp[i] += sh[i];

        float z = (g == 0) ? zp[0] : (g == 1) ? zp[1] : (g == 2) ? zp[2] : zp[3];
        z += b3v;
        float sp = fmaxf(z, 0.f) + __logf(1.f + __expf(-fabsf(z)));
        out[(q0 + qq) * NP + pmine] = bse[qq] * (1.f + sp);   // cw ~= alpha
    }
}

extern "C" void kernel_launch(void* const* d_in, const int* in_sizes, int n_in,
                              void* d_out, int out_size, void* d_ws, size_t ws_size,
                              hipStream_t stream) {
    const float* q  = (const float*)d_in[0];
    const float* pr = (const float*)d_in[1];
    const float* W1 = (const float*)d_in[2];
    const float* b1 = (const float*)d_in[3];
    const float* W2 = (const float*)d_in[4];
    const float* b2 = (const float*)d_in[5];
    const float* W3 = (const float*)d_in[6];
    const float* b3 = (const float*)d_in[7];
    float* out = (float*)d_out;
    float* ws  = (float*)d_ws;

    _Float16* qh16 = (_Float16*)(ws + OFF_QH16);
    _Float16* ph16 = (_Float16*)(ws + OFF_PH16);
    _Float16* w2f  = (_Float16*)(ws + OFF_W2F);

    prep_kernel<<<145, 256, 0, stream>>>(q, pr, W1, b1, W2, qh16, ph16, w2f);
    main_kernel<<<NQ / QB, 256, 0, stream>>>(qh16, ph16, w2f, q, pr,
                                             b2, W3, b3, out);
}

// Round 11
// 31.773 us; speedup vs baseline: 1.1062x; 1.0229x over previous
//
#include <hip/hip_runtime.h>
#include <hip/hip_bf16.h>
#include <hip/hip_fp16.h>

// Problem constants
#define D    128
#define NQ   2048
#define NP   256
#define H1   128
#define H2   64
#define QB   4     // q-rows per main block -> grid 512 = 2 blocks/CU

typedef __attribute__((ext_vector_type(8))) _Float16 f16x8;
typedef __attribute__((ext_vector_type(2))) __fp16   h16x2;   // cvt_pkrtz/fdot2 type
typedef __attribute__((ext_vector_type(4))) float    f32x4;

// ---------------------------------------------------------------------------
// Workspace layout (float units):
//   qh16  [NQ][H1] f16   q @ W1q^T + b1        off 0       (131072 f32 slots)
//   ph16  [NP][H1] f16   p @ W1p^T             off 131072  (16384)
//   w2f   [H2][H1] f16   cast of W2            off 147456  (4096)
//   base  [NQ][NP] f32                          off 151552  (524288)
// ---------------------------------------------------------------------------
#define OFF_QH16 0
#define OFF_PH16 131072
#define OFF_W2F  147456
#define OFF_BASE 151552

static __device__ __forceinline__ f16x8 cvt8(float4 a, float4 b) {
    f16x8 f;
    f[0] = (_Float16)a.x; f[1] = (_Float16)a.y;
    f[2] = (_Float16)a.z; f[3] = (_Float16)a.w;
    f[4] = (_Float16)b.x; f[5] = (_Float16)b.y;
    f[6] = (_Float16)b.z; f[7] = (_Float16)b.w;
    return f;
}

// ---------------------------------------------------------------------------
// Launch 1 (no internal deps):
//   bx   0..127  : q-proj -> qh16 (16 q rows each), bias folded
//   bx 128..143  : p-proj -> ph16 (16 p rows each)
//   bx 144       : W2 -> f16 cast
//   bx 145..272  : base tile (16 q x 256 p): dist^2 via f16 MFMA, norms inline
// All global loads hoisted ahead of MFMA chains.
// ---------------------------------------------------------------------------
__global__ void __launch_bounds__(256)
prep_base_kernel(const float* __restrict__ q, const float* __restrict__ p,
                 const float* __restrict__ W1, const float* __restrict__ b1,
                 const float* __restrict__ W2,
                 _Float16* __restrict__ qh16, _Float16* __restrict__ ph16,
                 _Float16* __restrict__ w2f, float* __restrict__ baseM) {
    int bx = blockIdx.x, tid = threadIdx.x;
    int lane = tid & 63, w = tid >> 6;
    int lo = lane & 15, g = lane >> 4;

    if (bx == 144) {
        for (int i = tid; i < H2 * H1; i += 256)
            w2f[i] = (_Float16)W2[i];
        return;
    }

    if (bx < 144) {                       // ---- projection blocks ----
        bool isQ = bx < 128;
        const float* X = isQ ? q : p;
        int r0 = isQ ? bx * 16 : (bx - 128) * 16;
        int woff = isQ ? 0 : D;
        _Float16* hout = isQ ? qh16 : ph16;
        int ob = w * 32;

        float4 ar[4][2], br[2][4][2];
        #pragma unroll
        for (int ks = 0; ks < 4; ++ks) {
            const float* src = X + (r0 + lo) * D + ks * 32 + g * 8;
            ar[ks][0] = *(const float4*)src;
            ar[ks][1] = *(const float4*)(src + 4);
        }
        #pragma unroll
        for (int n = 0; n < 2; ++n)
            #pragma unroll
            for (int ks = 0; ks < 4; ++ks) {
                const float* src = W1 + (ob + n * 16 + lo) * (2 * D) + woff + ks * 32 + g * 8;
                br[n][ks][0] = *(const float4*)src;
                br[n][ks][1] = *(const float4*)(src + 4);
            }
        f16x8 A[4];
        #pragma unroll
        for (int ks = 0; ks < 4; ++ks) A[ks] = cvt8(ar[ks][0], ar[ks][1]);

        f32x4 C[2];
        C[0] = (f32x4){0.f, 0.f, 0.f, 0.f};
        C[1] = (f32x4){0.f, 0.f, 0.f, 0.f};
        #pragma unroll
        for (int n = 0; n < 2; ++n)
            #pragma unroll
            for (int ks = 0; ks < 4; ++ks)
                C[n] = __builtin_amdgcn_mfma_f32_16x16x32_f16(
                    A[ks], cvt8(br[n][ks][0], br[n][ks][1]), C[n], 0, 0, 0);
        #pragma unroll
        for (int n = 0; n < 2; ++n) {
            int o = ob + n * 16 + lo;
            float bv = isQ ? b1[o] : 0.f;
            #pragma unroll
            for (int r = 0; r < 4; ++r)
                hout[(r0 + g * 4 + r) * H1 + o] = (_Float16)(C[n][r] + bv);
        }
        return;
    }

    // ---- base tiles: q rows r0..r0+15, wave w owns p [64w,64w+64)
    int r0 = (bx - 145) * 16;

    float4 qr[4][2];
    #pragma unroll
    for (int ks = 0; ks < 4; ++ks) {
        const float* src = q + (r0 + lo) * D + ks * 32 + g * 8;
        qr[ks][0] = *(const float4*)src;
        qr[ks][1] = *(const float4*)(src + 4);
    }
    float4 pr_[4][4][2];
    #pragma unroll
    for (int n = 0; n < 4; ++n) {
        int pcol = w * 64 + n * 16 + lo;
        #pragma unroll
        for (int ks = 0; ks < 4; ++ks) {
            const float* src = p + pcol * D + ks * 32 + g * 8;
            pr_[n][ks][0] = *(const float4*)src;
            pr_[n][ks][1] = *(const float4*)(src + 4);
        }
    }
    f16x8 A[4];
    float asq = 0.f;
    #pragma unroll
    for (int ks = 0; ks < 4; ++ks) {
        float4 a = qr[ks][0], b = qr[ks][1];
        asq += a.x * a.x + a.y * a.y + a.z * a.z + a.w * a.w
             + b.x * b.x + b.y * b.y + b.z * b.z + b.w * b.w;
        A[ks] = cvt8(a, b);
    }
    asq += __shfl_xor(asq, 16);
    asq += __shfl_xor(asq, 32);

    f32x4 C[4];
    float psq[4];
    #pragma unroll
    for (int n = 0; n < 4; ++n) {
        C[n] = (f32x4){0.f, 0.f, 0.f, 0.f};
        psq[n] = 0.f;
        #pragma unroll
        for (int ks = 0; ks < 4; ++ks) {
            float4 a = pr_[n][ks][0], b = pr_[n][ks][1];
            psq[n] += a.x * a.x + a.y * a.y + a.z * a.z + a.w * a.w
                    + b.x * b.x + b.y * b.y + b.z * b.z + b.w * b.w;
            C[n] = __builtin_amdgcn_mfma_f32_16x16x32_f16(A[ks], cvt8(a, b), C[n], 0, 0, 0);
        }
        psq[n] += __shfl_xor(psq[n], 16);
        psq[n] += __shfl_xor(psq[n], 32);
    }
    #pragma unroll
    for (int n = 0; n < 4; ++n) {
        int pcol = w * 64 + n * 16 + lo;
        #pragma unroll
        for (int r = 0; r < 4; ++r) {
            float qnv = __shfl(asq, g * 4 + r);
            baseM[(r0 + g * 4 + r) * NP + pcol] =
                fmaxf(qnv + psq[n] - 2.f * C[n][r], 0.f);
        }
    }
}

// ---------------------------------------------------------------------------
// Main (R8 + forced register residency): QB=4 q x 256 p per block, grid 512
// (2 blocks/CU = 2 waves/SIMD). Wave w owns p [64w,64w+64).
// P and Af are PINNED in VGPRs via opaque asm redefinition -- the compiler
// cannot rematerialize the global loads inside the q-loop (the R1..R10
// kernels all silently spilled/remat'd: e.g. R7 reported VGPR=84 while the
// design needs ~140 live). qk uses a 2-slot parity ring (32 VGPR, static
// indices) so peak pressure ~225 < 256 cap.
// ---------------------------------------------------------------------------
__global__ void __launch_bounds__(256, 2)
main_kernel(const _Float16* __restrict__ qh16, const _Float16* __restrict__ ph16,
            const _Float16* __restrict__ w2f,
            const float* __restrict__ b2, const float* __restrict__ w3,
            const float* __restrict__ b3,
            const float* __restrict__ baseM, float* __restrict__ out) {
    __shared__ _Float16 qh_s[QB * H1];   // 1 KB
    int tid = threadIdx.x, lane = tid & 63, w = tid >> 6;
    int lo = lane & 15, g = lane >> 4;
    int q0 = blockIdx.x * QB;

    if (tid < (QB * H1) / 8)
        ((uint4*)qh_s)[tid] = ((const uint4*)(qh16 + q0 * H1))[tid];

    // prefetch baseM (hidden under setup)
    int pmine = w * 64 + lane;
    float bse[QB];
    #pragma unroll
    for (int qq = 0; qq < QB; ++qq)
        bse[qq] = baseM[(q0 + qq) * NP + pmine];

    // ph fragments [n][ks], register-resident (64 VGPR), PINNED
    f16x8 P[4][4];
    #pragma unroll
    for (int n = 0; n < 4; ++n)
        #pragma unroll
        for (int ks = 0; ks < 4; ++ks) {
            P[n][ks] = *(const f16x8*)(ph16 + (w * 64 + n * 16 + lo) * H1 + ks * 32 + g * 8);
            asm volatile("" : "+v"(P[n][ks]));
        }

    // W2 fragments [m][ks], register-resident (64 VGPR), PINNED
    f16x8 Af[4][4];
    #pragma unroll
    for (int m = 0; m < 4; ++m)
        #pragma unroll
        for (int ks = 0; ks < 4; ++ks) {
            Af[m][ks] = *(const f16x8*)(w2f + (m * 16 + lo) * H1 + ks * 32 + g * 8);
            asm volatile("" : "+v"(Af[m][ks]));
        }

    // packed epilogue constants: o = m*16 + g*4 + {0..3}  (16 VGPR)
    h16x2 b2p[4][2], w3p[4][2];
    #pragma unroll
    for (int m = 0; m < 4; ++m) {
        float4 bb = *(const float4*)(b2 + m * 16 + g * 4);
        float4 ww = *(const float4*)(w3 + m * 16 + g * 4);
        b2p[m][0] = __builtin_amdgcn_cvt_pkrtz(bb.x, bb.y);
        b2p[m][1] = __builtin_amdgcn_cvt_pkrtz(bb.z, bb.w);
        w3p[m][0] = __builtin_amdgcn_cvt_pkrtz(ww.x, ww.y);
        w3p[m][1] = __builtin_amdgcn_cvt_pkrtz(ww.z, ww.w);
    }
    float b3v = b3[0];
    const f16x8 zz = {};
    const h16x2 z2 = {};
    const f32x4 Zv = (f32x4){0.f, 0.f, 0.f, 0.f};
    __syncthreads();

    // qk parity ring (2 x 4 frags = 32 VGPR, all indices compile-time)
    f16x8 qkr[2][4];
    #pragma unroll
    for (int ks = 0; ks < 4; ++ks)
        qkr[0][ks] = *(const f16x8*)(qh_s + 0 * H1 + ks * 32 + g * 8);

    #pragma unroll
    for (int qq = 0; qq < QB; ++qq) {
        float zp[4];
        #pragma unroll
        for (int hh = 0; hh < 2; ++hh) {
            f32x4 C[4][2];
            #pragma unroll
            for (int ks = 0; ks < 4; ++ks) {
                f16x8 B0 = __builtin_elementwise_max(P[2 * hh + 0][ks] + qkr[qq & 1][ks], zz);
                f16x8 B1 = __builtin_elementwise_max(P[2 * hh + 1][ks] + qkr[qq & 1][ks], zz);
                #pragma unroll
                for (int m = 0; m < 4; ++m) {
                    if (ks == 0) {   // constant zero acc: no per-q C re-zero
                        C[m][0] = __builtin_amdgcn_mfma_f32_16x16x32_f16(Af[m][0], B0, Zv, 0, 0, 0);
                        C[m][1] = __builtin_amdgcn_mfma_f32_16x16x32_f16(Af[m][0], B1, Zv, 0, 0, 0);
                    } else {
                        C[m][0] = __builtin_amdgcn_mfma_f32_16x16x32_f16(Af[m][ks], B0, C[m][0], 0, 0, 0);
                        C[m][1] = __builtin_amdgcn_mfma_f32_16x16x32_f16(Af[m][ks], B1, C[m][1], 0, 0, 0);
                    }
                }
            }
            // prefetch next q's qk into the opposite ring slot (after half 0)
            if (hh == 0 && qq + 1 < QB) {
                #pragma unroll
                for (int ks = 0; ks < 4; ++ks)
                    qkr[(qq + 1) & 1][ks] = *(const f16x8*)(qh_s + (qq + 1) * H1 + ks * 32 + g * 8);
            }
            // packed-f16 epilogue: h2 = relu(C+b2) (f16), z += h2 . w3 (dot2)
            #pragma unroll
            for (int n2 = 0; n2 < 2; ++n2) {
                float sA = 0.f, sB = 0.f;
                #pragma unroll
                for (int m = 0; m < 4; ++m) {
                    h16x2 c01 = __builtin_amdgcn_cvt_pkrtz(C[m][n2][0], C[m][n2][1]);
                    h16x2 c23 = __builtin_amdgcn_cvt_pkrtz(C[m][n2][2], C[m][n2][3]);
                    h16x2 h01 = __builtin_elementwise_max(c01 + b2p[m][0], z2);
                    h16x2 h23 = __builtin_elementwise_max(c23 + b2p[m][1], z2);
                    sA = __builtin_amdgcn_fdot2(h01, w3p[m][0], sA, false);
                    sB = __builtin_amdgcn_fdot2(h23, w3p[m][1], sB, false);
                }
                zp[2 * hh + n2] = sA + sB;
            }
        }
        // batched cross-lane reduction (ILP across the 4 values)
        float sh[4];
        #pragma unroll
        for (int i = 0; i < 4; ++i) sh[i] = __shfl_xor(zp[i], 16);
        #pragma unroll
        for (int i = 0; i < 4; ++i) zp[i] += sh[i];
        #pragma unroll
        for (int i = 0; i < 4; ++i) sh[i] = __shfl_xor(zp[i], 32);
        #pragma unroll
        for (int i = 0; i < 4; ++i) zp[i] += sh[i];

        float z = (g == 0) ? zp[0] : (g == 1) ? zp[1] : (g == 2) ? zp[2] : zp[3];
        z += b3v;
        float sp = fmaxf(z, 0.f) + __logf(1.f + __expf(-fabsf(z)));
        out[(q0 + qq) * NP + pmine] = bse[qq] * (1.f + sp);   // cw ~= alpha
    }
}

extern "C" void kernel_launch(void* const* d_in, const int* in_sizes, int n_in,
                              void* d_out, int out_size, void* d_ws, size_t ws_size,
                              hipStream_t stream) {
    const float* q  = (const float*)d_in[0];
    const float* pr = (const float*)d_in[1];
    const float* W1 = (const float*)d_in[2];
    const float* b1 = (const float*)d_in[3];
    const float* W2 = (const float*)d_in[4];
    const float* b2 = (const float*)d_in[5];
    const float* W3 = (const float*)d_in[6];
    const float* b3 = (const float*)d_in[7];
    float* out = (float*)d_out;
    float* ws  = (float*)d_ws;

    _Float16* qh16 = (_Float16*)(ws + OFF_QH16);
    _Float16* ph16 = (_Float16*)(ws + OFF_PH16);
    _Float16* w2f  = (_Float16*)(ws + OFF_W2F);
    float* baseM = ws + OFF_BASE;

    prep_base_kernel<<<273, 256, 0, stream>>>(q, pr, W1, b1, W2,
                                              qh16, ph16, w2f, baseM);
    main_kernel<<<NQ / QB, 256, 0, stream>>>(qh16, ph16, w2f, b2, W3, b3, baseM, out);
}

// Round 12
// 25.996 us; speedup vs baseline: 1.3520x; 1.2223x over previous
//
#include <hip/hip_runtime.h>
#include <hip/hip_bf16.h>
#include <hip/hip_fp16.h>

// Problem constants
#define D    128
#define NQ   2048
#define NP   256
#define H1   128
#define H2   64
#define QBW  4     // q-rows per WAVE in main; block covers 8 q (2 wave-halves)

typedef __attribute__((ext_vector_type(8))) _Float16 f16x8;
typedef __attribute__((ext_vector_type(2))) __fp16   h16x2;   // cvt_pkrtz/fdot2 type
typedef __attribute__((ext_vector_type(4))) float    f32x4;

// Workspace layout (float units)
#define OFF_QH16 0
#define OFF_PH16 131072
#define OFF_W2F  147456
#define OFF_BASE 151552

static __device__ __forceinline__ f16x8 cvt8(float4 a, float4 b) {
    f16x8 f;
    f[0] = (_Float16)a.x; f[1] = (_Float16)a.y;
    f[2] = (_Float16)a.z; f[3] = (_Float16)a.w;
    f[4] = (_Float16)b.x; f[5] = (_Float16)b.y;
    f[6] = (_Float16)b.z; f[7] = (_Float16)b.w;
    return f;
}

// ---------------------------------------------------------------------------
// Prep (identical to R8): 273 blocks, no internal deps.
//   bx 0..127: q-proj -> qh16;  128..143: p-proj -> ph16;  144: W2 cast;
//   145..272: base tiles (16q x 256p) -> baseM.
// ---------------------------------------------------------------------------
__global__ void __launch_bounds__(256)
prep_base_kernel(const float* __restrict__ q, const float* __restrict__ p,
                 const float* __restrict__ W1, const float* __restrict__ b1,
                 const float* __restrict__ W2,
                 _Float16* __restrict__ qh16, _Float16* __restrict__ ph16,
                 _Float16* __restrict__ w2f, float* __restrict__ baseM) {
    int bx = blockIdx.x, tid = threadIdx.x;
    int lane = tid & 63, w = tid >> 6;
    int lo = lane & 15, g = lane >> 4;

    if (bx == 144) {
        for (int i = tid; i < H2 * H1; i += 256)
            w2f[i] = (_Float16)W2[i];
        return;
    }

    if (bx < 144) {                       // ---- projection blocks ----
        bool isQ = bx < 128;
        const float* X = isQ ? q : p;
        int r0 = isQ ? bx * 16 : (bx - 128) * 16;
        int woff = isQ ? 0 : D;
        _Float16* hout = isQ ? qh16 : ph16;
        int ob = w * 32;

        float4 ar[4][2], br[2][4][2];
        #pragma unroll
        for (int ks = 0; ks < 4; ++ks) {
            const float* src = X + (r0 + lo) * D + ks * 32 + g * 8;
            ar[ks][0] = *(const float4*)src;
            ar[ks][1] = *(const float4*)(src + 4);
        }
        #pragma unroll
        for (int n = 0; n < 2; ++n)
            #pragma unroll
            for (int ks = 0; ks < 4; ++ks) {
                const float* src = W1 + (ob + n * 16 + lo) * (2 * D) + woff + ks * 32 + g * 8;
                br[n][ks][0] = *(const float4*)src;
                br[n][ks][1] = *(const float4*)(src + 4);
            }
        f16x8 A[4];
        #pragma unroll
        for (int ks = 0; ks < 4; ++ks) A[ks] = cvt8(ar[ks][0], ar[ks][1]);

        f32x4 C[2];
        C[0] = (f32x4){0.f, 0.f, 0.f, 0.f};
        C[1] = (f32x4){0.f, 0.f, 0.f, 0.f};
        #pragma unroll
        for (int n = 0; n < 2; ++n)
            #pragma unroll
            for (int ks = 0; ks < 4; ++ks)
                C[n] = __builtin_amdgcn_mfma_f32_16x16x32_f16(
                    A[ks], cvt8(br[n][ks][0], br[n][ks][1]), C[n], 0, 0, 0);
        #pragma unroll
        for (int n = 0; n < 2; ++n) {
            int o = ob + n * 16 + lo;
            float bv = isQ ? b1[o] : 0.f;
            #pragma unroll
            for (int r = 0; r < 4; ++r)
                hout[(r0 + g * 4 + r) * H1 + o] = (_Float16)(C[n][r] + bv);
        }
        return;
    }

    // ---- base tiles: q rows r0..r0+15, wave w owns p [64w,64w+64)
    int r0 = (bx - 145) * 16;

    float4 qr[4][2];
    #pragma unroll
    for (int ks = 0; ks < 4; ++ks) {
        const float* src = q + (r0 + lo) * D + ks * 32 + g * 8;
        qr[ks][0] = *(const float4*)src;
        qr[ks][1] = *(const float4*)(src + 4);
    }
    float4 pr_[4][4][2];
    #pragma unroll
    for (int n = 0; n < 4; ++n) {
        int pcol = w * 64 + n * 16 + lo;
        #pragma unroll
        for (int ks = 0; ks < 4; ++ks) {
            const float* src = p + pcol * D + ks * 32 + g * 8;
            pr_[n][ks][0] = *(const float4*)src;
            pr_[n][ks][1] = *(const float4*)(src + 4);
        }
    }
    f16x8 A[4];
    float asq = 0.f;
    #pragma unroll
    for (int ks = 0; ks < 4; ++ks) {
        float4 a = qr[ks][0], b = qr[ks][1];
        asq += a.x * a.x + a.y * a.y + a.z * a.z + a.w * a.w
             + b.x * b.x + b.y * b.y + b.z * b.z + b.w * b.w;
        A[ks] = cvt8(a, b);
    }
    asq += __shfl_xor(asq, 16);
    asq += __shfl_xor(asq, 32);

    f32x4 C[4];
    float psq[4];
    #pragma unroll
    for (int n = 0; n < 4; ++n) {
        C[n] = (f32x4){0.f, 0.f, 0.f, 0.f};
        psq[n] = 0.f;
        #pragma unroll
        for (int ks = 0; ks < 4; ++ks) {
            float4 a = pr_[n][ks][0], b = pr_[n][ks][1];
            psq[n] += a.x * a.x + a.y * a.y + a.z * a.z + a.w * a.w
                    + b.x * b.x + b.y * b.y + b.z * b.z + b.w * b.w;
            C[n] = __builtin_amdgcn_mfma_f32_16x16x32_f16(A[ks], cvt8(a, b), C[n], 0, 0, 0);
        }
        psq[n] += __shfl_xor(psq[n], 16);
        psq[n] += __shfl_xor(psq[n], 32);
    }
    #pragma unroll
    for (int n = 0; n < 4; ++n) {
        int pcol = w * 64 + n * 16 + lo;
        #pragma unroll
        for (int r = 0; r < 4; ++r) {
            float qnv = __shfl(asq, g * 4 + r);
            baseM[(r0 + g * 4 + r) * NP + pcol] =
                fmaxf(qnv + psq[n] - 2.f * C[n][r], 0.f);
        }
    }
}

// ---------------------------------------------------------------------------
// Main (R12): 512-thread blocks, grid 256 = 1 block/CU. Block = 8 q x 256 p.
// Wave w: p-range (w&3)*64, q-half (w>>2)*4 (4 q per wave, loop = R11 body).
// ph16 (64KB) + w2f (16KB) staged ONCE per block into LDS via coalesced
// burst (fixes R7's 36MB FETCH: every block was re-fetching operands cold
// after the poison fills flush L2/L3 -> per-block setup latency wall).
// LDS rows are 256B; frag reads would be 16-way bank conflicts, so stage
// and read with XOR swizzle byte ^= (row&7)<<4 (both sides) -> 2-way, free.
// ---------------------------------------------------------------------------
__global__ void __launch_bounds__(512, 2)
main_kernel(const _Float16* __restrict__ qh16, const _Float16* __restrict__ ph16,
            const _Float16* __restrict__ w2f,
            const float* __restrict__ b2, const float* __restrict__ w3,
            const float* __restrict__ b3,
            const float* __restrict__ baseM, float* __restrict__ out) {
    extern __shared__ char lds[];
    char* ph_s = lds;                            // 65536 B, swizzled
    char* w2_s = lds + 65536;                    // 16384 B, swizzled
    _Float16* qh_s = (_Float16*)(lds + 65536 + 16384);   // 2 KB linear

    int tid = threadIdx.x, lane = tid & 63, w = tid >> 6;   // w 0..7
    int lo = lane & 15, g = lane >> 4;
    int wp = w & 3;                 // p-group
    int q0w = blockIdx.x * 8 + (w >> 2) * 4;     // this wave's first q

    // ---- stage ph16 (8 iters) + w2f (2 iters), swizzled dst, linear src ----
    #pragma unroll
    for (int it = 0; it < 8; ++it) {
        int i16 = (it * 512 + tid) * 16;
        int row = i16 >> 8;
        *(uint4*)(ph_s + (i16 ^ ((row & 7) << 4))) =
            *(const uint4*)((const char*)ph16 + i16);
    }
    #pragma unroll
    for (int it = 0; it < 2; ++it) {
        int i16 = (it * 512 + tid) * 16;
        int row = i16 >> 8;
        *(uint4*)(w2_s + (i16 ^ ((row & 7) << 4))) =
            *(const uint4*)((const char*)w2f + i16);
    }
    if (tid < 128)
        ((uint4*)qh_s)[tid] = ((const uint4*)(qh16 + (size_t)blockIdx.x * 8 * H1))[tid];

    // prefetch baseM (independent, overlaps staging)
    int pmine = wp * 64 + lane;
    float bse[QBW];
    #pragma unroll
    for (int qq = 0; qq < QBW; ++qq)
        bse[qq] = baseM[(q0w + qq) * NP + pmine];

    // packed epilogue constants: o = m*16 + g*4 + {0..3}
    h16x2 b2p[4][2], w3p[4][2];
    #pragma unroll
    for (int m = 0; m < 4; ++m) {
        float4 bb = *(const float4*)(b2 + m * 16 + g * 4);
        float4 ww = *(const float4*)(w3 + m * 16 + g * 4);
        b2p[m][0] = __builtin_amdgcn_cvt_pkrtz(bb.x, bb.y);
        b2p[m][1] = __builtin_amdgcn_cvt_pkrtz(bb.z, bb.w);
        w3p[m][0] = __builtin_amdgcn_cvt_pkrtz(ww.x, ww.y);
        w3p[m][1] = __builtin_amdgcn_cvt_pkrtz(ww.z, ww.w);
    }
    float b3v = b3[0];
    const f16x8 zz = {};
    const h16x2 z2 = {};
    const f32x4 Zv = (f32x4){0.f, 0.f, 0.f, 0.f};
    __syncthreads();

    // ---- LDS -> registers, once (swizzled reads, 2-way conflicts = free) ----
    f16x8 P[4][4];
    #pragma unroll
    for (int n = 0; n < 4; ++n)
        #pragma unroll
        for (int ks = 0; ks < 4; ++ks) {
            int pp = wp * 64 + n * 16 + lo;
            int byte = (pp * 256 + ks * 64 + g * 16) ^ ((pp & 7) << 4);
            P[n][ks] = *(const f16x8*)(ph_s + byte);
            asm volatile("" : "+v"(P[n][ks]));
        }
    f16x8 Af[4][4];
    #pragma unroll
    for (int m = 0; m < 4; ++m)
        #pragma unroll
        for (int ks = 0; ks < 4; ++ks) {
            int row = m * 16 + lo;
            int byte = (row * 256 + ks * 64 + g * 16) ^ ((row & 7) << 4);
            Af[m][ks] = *(const f16x8*)(w2_s + byte);
            asm volatile("" : "+v"(Af[m][ks]));
        }

    // qk parity ring (2 x 4 frags, static indices)
    f16x8 qkr[2][4];
    int qb = (w >> 2) * 4;          // wave's q offset inside block
    #pragma unroll
    for (int ks = 0; ks < 4; ++ks)
        qkr[0][ks] = *(const f16x8*)(qh_s + qb * H1 + ks * 32 + g * 8);

    #pragma unroll
    for (int qq = 0; qq < QBW; ++qq) {
        float zp[4];
        #pragma unroll
        for (int hh = 0; hh < 2; ++hh) {
            f32x4 C[4][2];
            #pragma unroll
            for (int ks = 0; ks < 4; ++ks) {
                f16x8 B0 = __builtin_elementwise_max(P[2 * hh + 0][ks] + qkr[qq & 1][ks], zz);
                f16x8 B1 = __builtin_elementwise_max(P[2 * hh + 1][ks] + qkr[qq & 1][ks], zz);
                #pragma unroll
                for (int m = 0; m < 4; ++m) {
                    if (ks == 0) {
                        C[m][0] = __builtin_amdgcn_mfma_f32_16x16x32_f16(Af[m][0], B0, Zv, 0, 0, 0);
                        C[m][1] = __builtin_amdgcn_mfma_f32_16x16x32_f16(Af[m][0], B1, Zv, 0, 0, 0);
                    } else {
                        C[m][0] = __builtin_amdgcn_mfma_f32_16x16x32_f16(Af[m][ks], B0, C[m][0], 0, 0, 0);
                        C[m][1] = __builtin_amdgcn_mfma_f32_16x16x32_f16(Af[m][ks], B1, C[m][1], 0, 0, 0);
                    }
                }
            }
            if (hh == 0 && qq + 1 < QBW) {
                #pragma unroll
                for (int ks = 0; ks < 4; ++ks)
                    qkr[(qq + 1) & 1][ks] =
                        *(const f16x8*)(qh_s + (qb + qq + 1) * H1 + ks * 32 + g * 8);
            }
            #pragma unroll
            for (int n2 = 0; n2 < 2; ++n2) {
                float sA = 0.f, sB = 0.f;
                #pragma unroll
                for (int m = 0; m < 4; ++m) {
                    h16x2 c01 = __builtin_amdgcn_cvt_pkrtz(C[m][n2][0], C[m][n2][1]);
                    h16x2 c23 = __builtin_amdgcn_cvt_pkrtz(C[m][n2][2], C[m][n2][3]);
                    h16x2 h01 = __builtin_elementwise_max(c01 + b2p[m][0], z2);
                    h16x2 h23 = __builtin_elementwise_max(c23 + b2p[m][1], z2);
                    sA = __builtin_amdgcn_fdot2(h01, w3p[m][0], sA, false);
                    sB = __builtin_amdgcn_fdot2(h23, w3p[m][1], sB, false);
                }
                zp[2 * hh + n2] = sA + sB;
            }
        }
        float sh[4];
        #pragma unroll
        for (int i = 0; i < 4; ++i) sh[i] = __shfl_xor(zp[i], 16);
        #pragma unroll
        for (int i = 0; i < 4; ++i) zp[i] += sh[i];
        #pragma unroll
        for (int i = 0; i < 4; ++i) sh[i] = __shfl_xor(zp[i], 32);
        #pragma unroll
        for (int i = 0; i < 4; ++i) zp[i] += sh[i];

        float z = (g == 0) ? zp[0] : (g == 1) ? zp[1] : (g == 2) ? zp[2] : zp[3];
        z += b3v;
        float sp = fmaxf(z, 0.f) + __logf(1.f + __expf(-fabsf(z)));
        out[(q0w + qq) * NP + pmine] = bse[qq] * (1.f + sp);   // cw ~= alpha
    }
}

extern "C" void kernel_launch(void* const* d_in, const int* in_sizes, int n_in,
                              void* d_out, int out_size, void* d_ws, size_t ws_size,
                              hipStream_t stream) {
    const float* q  = (const float*)d_in[0];
    const float* pr = (const float*)d_in[1];
    const float* W1 = (const float*)d_in[2];
    const float* b1 = (const float*)d_in[3];
    const float* W2 = (const float*)d_in[4];
    const float* b2 = (const float*)d_in[5];
    const float* W3 = (const float*)d_in[6];
    const float* b3 = (const float*)d_in[7];
    float* out = (float*)d_out;
    float* ws  = (float*)d_ws;

    _Float16* qh16 = (_Float16*)(ws + OFF_QH16);
    _Float16* ph16 = (_Float16*)(ws + OFF_PH16);
    _Float16* w2f  = (_Float16*)(ws + OFF_W2F);
    float* baseM = ws + OFF_BASE;

    prep_base_kernel<<<273, 256, 0, stream>>>(q, pr, W1, b1, W2,
                                              qh16, ph16, w2f, baseM);
    int ldsBytes = 65536 + 16384 + 2048;
    main_kernel<<<NQ / 8, 512, ldsBytes, stream>>>(qh16, ph16, w2f,
                                                   b2, W3, b3, baseM, out);
}